// Round 1
// baseline (448.581 us; speedup 1.0000x reference)
//
#include <hip/hip_runtime.h>

#define NN 8
#define CI 64
#define CO 128
#define HH 128
#define WW 128

#define TILE 32
#define LT 36            // 32 + 2*2 halo
#define OCH 16           // output channels per block
#define ICH 4            // input channels staged per chunk
#define NTHREADS 256

__global__ __launch_bounds__(NTHREADS) void customConv_kernel(
    const float* __restrict__ in, const float* __restrict__ w,
    float* __restrict__ out) {
  __shared__ float s_in[ICH][LT * LT];
  __shared__ float s_T[LT * LT];          // running channel-sum tile
  __shared__ float s_w[ICH][9][OCH];      // even-tap weights

  const int tid  = threadIdx.x;
  const int tile = blockIdx.x;            // 16 spatial tiles (4x4 of 32x32)
  const int ocb  = blockIdx.y;            // 8 chunks of 16 output channels
  const int n    = blockIdx.z;            // batch
  const int ty0  = (tile >> 2) * TILE;
  const int tx0  = (tile & 3) * TILE;
  const int obase = ocb * OCH;

  const int prow = tid >> 5;              // 0..7
  const int pcol = tid & 31;              // 0..31

  float acc[OCH][4];
  #pragma unroll
  for (int o = 0; o < OCH; ++o)
    #pragma unroll
    for (int p = 0; p < 4; ++p) acc[o][p] = 0.f;

  for (int e = tid; e < LT * LT; e += NTHREADS) s_T[e] = 0.f;

  for (int ib = 0; ib < CI; ib += ICH) {
    __syncthreads();  // previous chunk's compute done before overwriting s_in

    // stage input chunk (zero-padded halo tile, ICH channels)
    for (int e = tid; e < ICH * LT * LT; e += NTHREADS) {
      const int ic = e / (LT * LT);
      const int rc = e - ic * (LT * LT);
      const int r = rc / LT, c = rc - r * LT;
      const int gy = ty0 + r - 2, gx = tx0 + c - 2;
      float v = 0.f;
      if (gy >= 0 && gy < HH && gx >= 0 && gx < WW)
        v = in[(((size_t)n * CI + (ib + ic)) * HH + gy) * WW + gx];
      s_in[ic][rc] = v;
    }
    // stage even-tap weights: [ic][tap][o]
    for (int e = tid; e < ICH * 9 * OCH; e += NTHREADS) {
      const int ic = e / (9 * OCH);
      const int rest = e - ic * (9 * OCH);
      const int tap = rest / OCH;
      const int o = rest - tap * OCH;
      const int ky = (tap / 3) * 2, kx = (tap % 3) * 2;
      s_w[ic][tap][o] =
          w[(((size_t)(obase + o) * CI + (ib + ic)) * 5 + ky) * 5 + kx];
    }
    __syncthreads();

    // fold this chunk into the channel-sum tile (each thread owns its e's)
    for (int e = tid; e < LT * LT; e += NTHREADS)
      s_T[e] += s_in[0][e] + s_in[1][e] + s_in[2][e] + s_in[3][e];

    // main 9-tap dilated conv accumulation
    #pragma unroll
    for (int ic = 0; ic < ICH; ++ic) {
      #pragma unroll
      for (int tap = 0; tap < 9; ++tap) {
        const int dy = (tap / 3) * 2, dx = (tap % 3) * 2;
        float wv[OCH];
        #pragma unroll
        for (int o = 0; o < OCH; ++o) wv[o] = s_w[ic][tap][o];
        #pragma unroll
        for (int p = 0; p < 4; ++p) {
          const float v = s_in[ic][(prow + p * 8 + dy) * LT + (pcol + dx)];
          #pragma unroll
          for (int o = 0; o < OCH; ++o) acc[o][p] = fmaf(wv[o], v, acc[o][p]);
        }
      }
    }
  }
  __syncthreads();  // s_T fully accumulated & visible

  const float mu = (float)((1.0 - 0.9) / 3.0);
  #pragma unroll
  for (int p = 0; p < 4; ++p) {
    const int r = prow + p * 8;
    float s = 0.f;
    #pragma unroll
    for (int ky = 0; ky < 5; ++ky)
      #pragma unroll
      for (int kx = 0; kx < 5; ++kx)
        if ((ky & 1) || (kx & 1))           // the 16 neighbor-mask taps
          s += s_T[(r + ky) * LT + (pcol + kx)];
    s *= mu;
    const int gy = ty0 + r, gx = tx0 + pcol;
    #pragma unroll
    for (int o = 0; o < OCH; ++o)
      out[(((size_t)n * CO + (obase + o)) * HH + gy) * WW + gx] = acc[o][p] + s;
  }
}

extern "C" void kernel_launch(void* const* d_in, const int* in_sizes, int n_in,
                              void* d_out, int out_size, void* d_ws, size_t ws_size,
                              hipStream_t stream) {
  const float* in = (const float*)d_in[0];
  const float* w  = (const float*)d_in[1];
  float* out      = (float*)d_out;
  dim3 grid(WW / TILE * (HH / TILE), CO / OCH, NN);  // 16 x 8 x 8
  customConv_kernel<<<grid, NTHREADS, 0, stream>>>(in, w, out);
}

// Round 2
// 85.708 us; speedup vs baseline: 5.2338x; 5.2338x over previous
//
#include <hip/hip_runtime.h>

typedef short short8 __attribute__((ext_vector_type(8)));
typedef float f32x4 __attribute__((ext_vector_type(4)));

#define NN 8
#define CI 64
#define CO 128
#define HH 128
#define WW 128
#define MU 0.033333333333333333f

#define TPY 8              // output tile rows
#define TPX 32             // output tile cols
#define HR 12              // halo rows (TPY + 4)
#define HC 36              // halo cols (TPX + 4)
#define NPOS (HR * HC)     // 432
#define WS_W_BYTES (9 * 128 * 64 * 2)   // 147456

__device__ __forceinline__ unsigned short f2bf(float f) {
  unsigned u = __float_as_uint(f);
  u += 0x7fffu + ((u >> 16) & 1u);     // round-to-nearest-even
  return (unsigned short)(u >> 16);
}

// ---- prep: repack even-tap weights to bf16 [tap][co][ic]; channel-sum plane T ----
__global__ __launch_bounds__(256) void prep_kernel(
    const float* __restrict__ in, const float* __restrict__ w,
    unsigned short* __restrict__ ws_w, float* __restrict__ ws_T) {
  const int bid = blockIdx.x, tid = threadIdx.x;
  if (bid < 288) {                       // 288*256 = 73728 = 9*128*64
    const int el = bid * 256 + tid;
    const int tap = el >> 13;            // /8192
    const int rem = el & 8191;
    const int co = rem >> 6, ic = rem & 63;
    const int ky = (tap / 3) * 2, kx = (tap % 3) * 2;
    ws_w[el] = f2bf(w[(co * 64 + ic) * 25 + ky * 5 + kx]);
  } else {                               // 512*256 = 131072 pixels
    const int p = (bid - 288) * 256 + tid;
    const int n = p >> 14;
    const int yx = p & 16383;
    const float* base = in + (size_t)n * CI * (HH * WW) + yx;
    float s = 0.f;
    #pragma unroll
    for (int ic = 0; ic < CI; ++ic) s += base[ic * (HH * WW)];
    ws_T[p] = s;
  }
}

// ---- main conv: implicit GEMM, 9 taps x K=64, bf16 MFMA 16x16x32 ----
__global__ __launch_bounds__(256, 2) void conv_kernel(
    const float* __restrict__ in, const unsigned short* __restrict__ ws_w,
    const float* __restrict__ ws_T, float* __restrict__ out) {
  __shared__ short8 in_lds[NPOS * 8];    // [pos][slot^(pos&7)], slot = 8-ic group
  __shared__ float T_lds[NPOS];

  const int tid = threadIdx.x;
  const int t = blockIdx.x;              // 64 spatial tiles (16 y x 4 x)
  const int n = blockIdx.y;
  const int ty0 = (t >> 2) * TPY;
  const int tx0 = (t & 3) * TPX;

  // ---- stage halo tile: fp32 global -> bf16, ic-contiguous, swizzled ----
  for (int e = tid; e < NPOS * 8; e += 256) {
    const int slot = e / NPOS;           // 0..7 (ic group)
    const int pos = e - slot * NPOS;
    const int r = pos / HC, c = pos - r * HC;
    const int gy = ty0 + r - 2, gx = tx0 + c - 2;
    const bool ok = (gy >= 0 && gy < HH && gx >= 0 && gx < WW);
    const long off = ((long)(n * CI + slot * 8) * HH + gy) * WW + gx;
    short8 pk;
    #pragma unroll
    for (int j = 0; j < 8; ++j) {
      const float v = ok ? in[off + (long)j * (HH * WW)] : 0.f;
      pk[j] = (short)f2bf(v);
    }
    in_lds[pos * 8 + (slot ^ (pos & 7))] = pk;
  }
  for (int e = tid; e < NPOS; e += 256) {
    const int r = e / HC, c = e - r * HC;
    const int gy = ty0 + r - 2, gx = tx0 + c - 2;
    T_lds[e] = (gy >= 0 && gy < HH && gx >= 0 && gx < WW)
                   ? ws_T[((size_t)n * HH + gy) * WW + gx] : 0.f;
  }
  __syncthreads();

  const int wave = tid >> 6;
  const int lane = tid & 63;
  const int lo = lane & 15;              // A row (co), B col (px), D col
  const int hi = lane >> 4;              // k group

  int py[4], pxc[4];
  #pragma unroll
  for (int f = 0; f < 4; ++f) {
    const int pb = wave * 64 + f * 16;   // wave owns 64 pixels, 4 frags of 16
    py[f] = pb >> 5;
    pxc[f] = (pb & 31) + lo;
  }

  f32x4 acc[8][4];
  #pragma unroll
  for (int cb = 0; cb < 8; ++cb)
    #pragma unroll
    for (int f = 0; f < 4; ++f) acc[cb][f] = (f32x4){0.f, 0.f, 0.f, 0.f};

  const short8* wsv = (const short8*)ws_w;   // [(tap*128+co)*8 + icslot]

  #pragma unroll
  for (int tap = 0; tap < 9; ++tap) {
    const int ty = (tap / 3) * 2, tx = (tap % 3) * 2;
    #pragma unroll
    for (int ks = 0; ks < 2; ++ks) {
      short8 bfrag[4];
      #pragma unroll
      for (int f = 0; f < 4; ++f) {
        const int pos = (py[f] + ty) * HC + (pxc[f] + tx);
        bfrag[f] = in_lds[pos * 8 + ((ks * 4 + hi) ^ (pos & 7))];
      }
      #pragma unroll
      for (int cb = 0; cb < 8; ++cb) {
        const short8 afrag = wsv[(tap * 128 + cb * 16 + lo) * 8 + ks * 4 + hi];
        #pragma unroll
        for (int f = 0; f < 4; ++f)
          acc[cb][f] = __builtin_amdgcn_mfma_f32_16x16x32_bf16(
              afrag, bfrag[f], acc[cb][f], 0, 0, 0);
      }
    }
  }

  // ---- neighbor term (fp32-exact) + store ----
  float nb[4];
  #pragma unroll
  for (int f = 0; f < 4; ++f) {
    float s = 0.f;
    #pragma unroll
    for (int ky = 0; ky < 5; ++ky)
      #pragma unroll
      for (int kx = 0; kx < 5; ++kx)
        if ((ky & 1) | (kx & 1))
          s += T_lds[(py[f] + ky) * HC + (pxc[f] + kx)];
    nb[f] = s * MU;
  }

  #pragma unroll
  for (int cb = 0; cb < 8; ++cb) {
    #pragma unroll
    for (int f = 0; f < 4; ++f) {
      const int gy = ty0 + py[f];
      const int gx = tx0 + pxc[f];
      #pragma unroll
      for (int q = 0; q < 4; ++q) {
        const int co = cb * 16 + hi * 4 + q;
        out[(((size_t)n * CO + co) * HH + gy) * WW + gx] = acc[cb][f][q] + nb[f];
      }
    }
  }
}

extern "C" void kernel_launch(void* const* d_in, const int* in_sizes, int n_in,
                              void* d_out, int out_size, void* d_ws, size_t ws_size,
                              hipStream_t stream) {
  const float* in = (const float*)d_in[0];
  const float* w  = (const float*)d_in[1];
  float* out = (float*)d_out;
  unsigned short* ws_w = (unsigned short*)d_ws;
  float* ws_T = (float*)((char*)d_ws + WS_W_BYTES);
  prep_kernel<<<dim3(288 + 512), 256, 0, stream>>>(in, w, ws_w, ws_T);
  conv_kernel<<<dim3(64, 8), 256, 0, stream>>>(in, ws_w, ws_T, out);
}

// Round 4
// 67.232 us; speedup vs baseline: 6.6721x; 1.2748x over previous
//
#include <hip/hip_runtime.h>

typedef short short8 __attribute__((ext_vector_type(8)));
typedef float f32x4 __attribute__((ext_vector_type(4)));

#define NN 8
#define CI 64
#define CO 128
#define HH 128
#define WW 128
#define PH 132             // padded (2-halo each side)
#define PW 132
#define MU 0.033333333333333333f

#define TPY 8              // output tile rows
#define TPX 32             // output tile cols
#define HR 12              // halo rows
#define HC 36              // halo cols
#define NPOS (HR * HC)     // 432

#define WS_W_BYTES (9 * 128 * 64 * 2)        // 147456
#define WS_T_OFF   WS_W_BYTES
#define WS_T_BYTES (NN * PH * PW * 4)        // 557568
#define WS_X_OFF   (WS_T_OFF + WS_T_BYTES)   // 705024
#define WS_X_BYTES ((size_t)NN * PH * PW * CI * 2)   // 17842176
#define WS_TOTAL   (WS_X_OFF + WS_X_BYTES)   // ~18.5 MB

__device__ __forceinline__ unsigned short f2bf(float f) {
  unsigned u = __float_as_uint(f);
  u += 0x7fffu + ((u >> 16) & 1u);     // round-to-nearest-even
  return (unsigned short)(u >> 16);
}

__device__ __forceinline__ void g2lds16(const void* g, void* l) {
  __builtin_amdgcn_global_load_lds(
      (const __attribute__((address_space(1))) unsigned int*)g,
      (__attribute__((address_space(3))) unsigned int*)l, 16, 0, 0);
}

// ================= FAST PATH (needs WS_TOTAL workspace) =================
// prep: bf16 NHWC padded repack + channel-sum plane T (padded) + weights
// grid: [0,512) pixel blocks, [512,520) border-zero, [520,556) weight repack
__global__ __launch_bounds__(256) void prep_kernel(
    const float* __restrict__ in, const float* __restrict__ w,
    unsigned short* __restrict__ ws_w, float* __restrict__ ws_T,
    short8* __restrict__ ws_x) {
  const int b = blockIdx.x, tid = threadIdx.x;
  if (b < 512) {
    __shared__ short8 lx[256][8];            // [px][slot^(px&7)]
    const int n = b >> 6, pair = b & 63;
    const int px = tid;
    const int r = pair * 2 + (px >> 7), x = px & 127;
    const float* src = in + ((size_t)(n * CI) * HH + r) * WW + x;
    float tsum = 0.f;
    #pragma unroll
    for (int g = 0; g < 8; ++g) {
      short8 pk;
      #pragma unroll
      for (int j = 0; j < 8; ++j) {
        const float v = src[(size_t)(g * 8 + j) * (HH * WW)];
        tsum += v;
        pk[j] = (short)f2bf(v);
      }
      lx[px][g ^ (px & 7)] = pk;
    }
    ws_T[(n * PH + r + 2) * PW + (x + 2)] = tsum;
    __syncthreads();
    #pragma unroll
    for (int it = 0; it < 8; ++it) {         // coalesced NHWC store, 16B/lane
      const int G = it * 256 + tid;
      const int px2 = G >> 3, g2 = G & 7;
      const int r2 = pair * 2 + (px2 >> 7), x2 = px2 & 127;
      ws_x[((size_t)(n * PH + r2 + 2) * PW + (x2 + 2)) * 8 + g2] =
          lx[px2][g2 ^ (px2 & 7)];
    }
  } else if (b < 520) {                      // zero the padded borders
    const int n = b - 512;
    const short8 z = {0, 0, 0, 0, 0, 0, 0, 0};
    for (int e = tid; e < 1040 * 8; e += 256) {
      const int px = e >> 3, g = e & 7;
      int y, x;
      if (px < 528) { const int r4 = px / 132; y = (r4 < 2) ? r4 : r4 + 128; x = px - r4 * 132; }
      else { const int q = px - 528; const int c4 = q >> 7; x = (c4 < 2) ? c4 : c4 + 128; y = 2 + (q & 127); }
      ws_x[((size_t)(n * PH + y) * PW + x) * 8 + g] = z;
    }
    for (int e = tid; e < 1040; e += 256) {
      int y, x;
      if (e < 528) { const int r4 = e / 132; y = (r4 < 2) ? r4 : r4 + 128; x = e - r4 * 132; }
      else { const int q = e - 528; const int c4 = q >> 7; x = (c4 < 2) ? c4 : c4 + 128; y = 2 + (q & 127); }
      ws_T[(n * PH + y) * PW + x] = 0.f;
    }
  } else {                                   // even-tap weights -> bf16 [tap][co][ic]
    const int base = (b - 520) * 2048;
    #pragma unroll
    for (int i = 0; i < 8; ++i) {
      const int el = base + i * 256 + tid;
      const int tap = el >> 13, rem = el & 8191;
      const int co = rem >> 6, ic = rem & 63;
      const int ky = (tap / 3) * 2, kx = (tap % 3) * 2;
      ws_w[el] = f2bf(w[(co * 64 + ic) * 25 + ky * 5 + kx]);
    }
  }
}

// conv: async-staged halo, 9 taps x K=64, bf16 MFMA 16x16x32
__global__ __launch_bounds__(256, 2) void conv_kernel(
    const unsigned short* __restrict__ ws_w, const float* __restrict__ ws_T,
    const unsigned short* __restrict__ ws_x, float* __restrict__ out) {
  __shared__ short8 in_lds[NPOS * 8];        // 55296 B, [pos][slot^(pos&7)]
  __shared__ float T_lds[NPOS];

  const int tid = threadIdx.x;
  const int wave = tid >> 6, lane = tid & 63;
  const int t = blockIdx.x;                  // 64 spatial tiles (16 y x 4 x)
  const int n = blockIdx.y;
  const int ty0 = (t >> 2) * TPY;
  const int tx0 = (t & 3) * TPX;

  // async halo stage: per wave-instr 8 pos x 8 chunks; source pre-swizzled
  for (int k = wave; k < 54; k += 4) {
    const int pos = k * 8 + (lane >> 3);
    const int r = pos / HC, c = pos - r * HC;
    const int chunk = (lane & 7) ^ (pos & 7);
    const unsigned short* g =
        ws_x + (((size_t)(n * PH + ty0 + r) * PW + (tx0 + c)) * 64 + chunk * 8);
    g2lds16(g, (char*)in_lds + k * 1024);
  }
  for (int e = tid; e < NPOS; e += 256) {
    const int r = e / HC, c = e - r * HC;
    T_lds[e] = ws_T[(n * PH + ty0 + r) * PW + (tx0 + c)];
  }
  __syncthreads();                           // drains vmcnt (incl. load_lds)

  const int lo = lane & 15;                  // A row (co), B col (px)
  const int hi = lane >> 4;                  // k group

  int py[4], pxc[4];
  #pragma unroll
  for (int f = 0; f < 4; ++f) {
    const int pb = wave * 64 + f * 16;
    py[f] = pb >> 5;
    pxc[f] = (pb & 31) + lo;
  }

  f32x4 acc[8][4];
  #pragma unroll
  for (int cb = 0; cb < 8; ++cb)
    #pragma unroll
    for (int f = 0; f < 4; ++f) acc[cb][f] = (f32x4){0.f, 0.f, 0.f, 0.f};

  const short8* wsv = (const short8*)ws_w;   // [(tap*128+co)*8 + icslot]

  #pragma unroll
  for (int tap = 0; tap < 9; ++tap) {
    const int ty = (tap / 3) * 2, tx = (tap % 3) * 2;
    #pragma unroll
    for (int ks = 0; ks < 2; ++ks) {
      short8 bfrag[4];
      #pragma unroll
      for (int f = 0; f < 4; ++f) {
        const int pos = (py[f] + ty) * HC + (pxc[f] + tx);
        bfrag[f] = in_lds[pos * 8 + ((ks * 4 + hi) ^ (pos & 7))];
      }
      #pragma unroll
      for (int cb = 0; cb < 8; ++cb) {
        const short8 afrag = wsv[(tap * 128 + cb * 16 + lo) * 8 + ks * 4 + hi];
        #pragma unroll
        for (int f = 0; f < 4; ++f)
          acc[cb][f] = __builtin_amdgcn_mfma_f32_16x16x32_bf16(
              afrag, bfrag[f], acc[cb][f], 0, 0, 0);
      }
    }
  }

  // neighbor term (fp32-exact) + store
  float nb[4];
  #pragma unroll
  for (int f = 0; f < 4; ++f) {
    float s = 0.f;
    #pragma unroll
    for (int ky = 0; ky < 5; ++ky)
      #pragma unroll
      for (int kx = 0; kx < 5; ++kx)
        if ((ky & 1) | (kx & 1))
          s += T_lds[(py[f] + ky) * HC + (pxc[f] + kx)];
    nb[f] = s * MU;
  }

  #pragma unroll
  for (int cb = 0; cb < 8; ++cb) {
    #pragma unroll
    for (int f = 0; f < 4; ++f) {
      const int gy = ty0 + py[f];
      const int gx = tx0 + pxc[f];
      #pragma unroll
      for (int q = 0; q < 4; ++q) {
        const int co = cb * 16 + hi * 4 + q;
        out[(((size_t)n * CO + co) * HH + gy) * WW + gx] = acc[cb][f][q] + nb[f];
      }
    }
  }
}

// ================= SAFE PATH (Round-2 proven, 705 KB ws) =================
__global__ __launch_bounds__(256) void prep_kernel_safe(
    const float* __restrict__ in, const float* __restrict__ w,
    unsigned short* __restrict__ ws_w, float* __restrict__ ws_T) {
  const int bid = blockIdx.x, tid = threadIdx.x;
  if (bid < 288) {
    const int el = bid * 256 + tid;
    const int tap = el >> 13;
    const int rem = el & 8191;
    const int co = rem >> 6, ic = rem & 63;
    const int ky = (tap / 3) * 2, kx = (tap % 3) * 2;
    ws_w[el] = f2bf(w[(co * 64 + ic) * 25 + ky * 5 + kx]);
  } else {
    const int p = (bid - 288) * 256 + tid;
    const int n = p >> 14;
    const int yx = p & 16383;
    const float* base = in + (size_t)n * CI * (HH * WW) + yx;
    float s = 0.f;
    #pragma unroll
    for (int ic = 0; ic < CI; ++ic) s += base[ic * (HH * WW)];
    ws_T[p] = s;
  }
}

__global__ __launch_bounds__(256, 2) void conv_kernel_safe(
    const float* __restrict__ in, const unsigned short* __restrict__ ws_w,
    const float* __restrict__ ws_T, float* __restrict__ out) {
  __shared__ short8 in_lds[NPOS * 8];
  __shared__ float T_lds[NPOS];

  const int tid = threadIdx.x;
  const int t = blockIdx.x;
  const int n = blockIdx.y;
  const int ty0 = (t >> 2) * TPY;
  const int tx0 = (t & 3) * TPX;

  for (int e = tid; e < NPOS * 8; e += 256) {
    const int slot = e / NPOS;
    const int pos = e - slot * NPOS;
    const int r = pos / HC, c = pos - r * HC;
    const int gy = ty0 + r - 2, gx = tx0 + c - 2;
    const bool ok = (gy >= 0 && gy < HH && gx >= 0 && gx < WW);
    const long off = ((long)(n * CI + slot * 8) * HH + gy) * WW + gx;
    short8 pk;
    #pragma unroll
    for (int j = 0; j < 8; ++j) {
      const float v = ok ? in[off + (long)j * (HH * WW)] : 0.f;
      pk[j] = (short)f2bf(v);
    }
    in_lds[pos * 8 + (slot ^ (pos & 7))] = pk;
  }
  for (int e = tid; e < NPOS; e += 256) {
    const int r = e / HC, c = e - r * HC;
    const int gy = ty0 + r - 2, gx = tx0 + c - 2;
    T_lds[e] = (gy >= 0 && gy < HH && gx >= 0 && gx < WW)
                   ? ws_T[((size_t)n * HH + gy) * WW + gx] : 0.f;
  }
  __syncthreads();

  const int wave = tid >> 6;
  const int lane = tid & 63;
  const int lo = lane & 15;
  const int hi = lane >> 4;

  int py[4], pxc[4];
  #pragma unroll
  for (int f = 0; f < 4; ++f) {
    const int pb = wave * 64 + f * 16;
    py[f] = pb >> 5;
    pxc[f] = (pb & 31) + lo;
  }

  f32x4 acc[8][4];
  #pragma unroll
  for (int cb = 0; cb < 8; ++cb)
    #pragma unroll
    for (int f = 0; f < 4; ++f) acc[cb][f] = (f32x4){0.f, 0.f, 0.f, 0.f};

  const short8* wsv = (const short8*)ws_w;

  #pragma unroll
  for (int tap = 0; tap < 9; ++tap) {
    const int ty = (tap / 3) * 2, tx = (tap % 3) * 2;
    #pragma unroll
    for (int ks = 0; ks < 2; ++ks) {
      short8 bfrag[4];
      #pragma unroll
      for (int f = 0; f < 4; ++f) {
        const int pos = (py[f] + ty) * HC + (pxc[f] + tx);
        bfrag[f] = in_lds[pos * 8 + ((ks * 4 + hi) ^ (pos & 7))];
      }
      #pragma unroll
      for (int cb = 0; cb < 8; ++cb) {
        const short8 afrag = wsv[(tap * 128 + cb * 16 + lo) * 8 + ks * 4 + hi];
        #pragma unroll
        for (int f = 0; f < 4; ++f)
          acc[cb][f] = __builtin_amdgcn_mfma_f32_16x16x32_bf16(
              afrag, bfrag[f], acc[cb][f], 0, 0, 0);
      }
    }
  }

  float nb[4];
  #pragma unroll
  for (int f = 0; f < 4; ++f) {
    float s = 0.f;
    #pragma unroll
    for (int ky = 0; ky < 5; ++ky)
      #pragma unroll
      for (int kx = 0; kx < 5; ++kx)
        if ((ky & 1) | (kx & 1))
          s += T_lds[(py[f] + ky) * HC + (pxc[f] + kx)];
    nb[f] = s * MU;
  }

  #pragma unroll
  for (int cb = 0; cb < 8; ++cb) {
    #pragma unroll
    for (int f = 0; f < 4; ++f) {
      const int gy = ty0 + py[f];
      const int gx = tx0 + pxc[f];
      #pragma unroll
      for (int q = 0; q < 4; ++q) {
        const int co = cb * 16 + hi * 4 + q;
        out[(((size_t)n * CO + co) * HH + gy) * WW + gx] = acc[cb][f][q] + nb[f];
      }
    }
  }
}

extern "C" void kernel_launch(void* const* d_in, const int* in_sizes, int n_in,
                              void* d_out, int out_size, void* d_ws, size_t ws_size,
                              hipStream_t stream) {
  const float* in = (const float*)d_in[0];
  const float* w  = (const float*)d_in[1];
  float* out = (float*)d_out;
  unsigned short* ws_w = (unsigned short*)d_ws;

  if (ws_size >= WS_TOTAL) {
    float* ws_T = (float*)((char*)d_ws + WS_T_OFF);
    short8* ws_x = (short8*)((char*)d_ws + WS_X_OFF);
    prep_kernel<<<dim3(556), 256, 0, stream>>>(in, w, ws_w, ws_T, ws_x);
    conv_kernel<<<dim3(64, NN), 256, 0, stream>>>(
        ws_w, ws_T, (const unsigned short*)ws_x, out);
  } else {
    float* ws_T = (float*)((char*)d_ws + WS_W_BYTES);
    prep_kernel_safe<<<dim3(288 + 512), 256, 0, stream>>>(in, w, ws_w, ws_T);
    conv_kernel_safe<<<dim3(64, NN), 256, 0, stream>>>(in, ws_w, ws_T, out);
  }
}